// Round 9
// baseline (1173.133 us; speedup 1.0000x reference)
//
#include <hip/hip_runtime.h>

// Problem constants (from reference): T=8, D=512, H=100, C=2, NEG=1
constexpr int D_ = 512;
constexpr int H_ = 100;
constexpr int C_ = 2;
constexpr int T_ = 8;

constexpr int TE  = 128;        // edges per tile
constexpr int DC  = 32;         // D-chunk (floats) = one 128B line per row = one MFMA K
constexpr int NC  = D_ / DC;    // 16 chunks
constexpr int NTH = 512;        // 8 waves; only waves 0-3 issue global ops
constexpr int GRID_MAIN = 256;  // persistent: one block per CU
constexpr int SB  = 128;        // sort segments / blocks
constexpr int STH = 256;        // threads per sort block

// ws ints: [0:8) typeBase | [8:16) typeCount | [16:25) tileBase | [26] tile ctr
//          [32:32+SB*8) hist/blockBase | [1056:1056+E) sorted_e
constexpr int WS_CTR  = 26;
constexpr int WS_HIST = 32;
constexpr int WS_SORTED = 32 + SB * T_;   // 1056

typedef __attribute__((ext_vector_type(8))) short bf16x8;
typedef __attribute__((ext_vector_type(4))) float f32x4;

__device__ __forceinline__ unsigned short bfhi(float x) {
    return (unsigned short)(__builtin_bit_cast(unsigned int, x) >> 16);
}
__device__ __forceinline__ float bfback(unsigned short u) {
    return __builtin_bit_cast(float, (unsigned int)u << 16);
}

// ---------------------------------------------------------------------------
// K1: per-segment histogram. SB blocks x STH threads.
// ---------------------------------------------------------------------------
__global__ __launch_bounds__(STH) void k_hist(const int* __restrict__ et, int E, int seg,
                                              int* __restrict__ hist) {
    __shared__ int hb[T_];
    const int b = blockIdx.x, tid = threadIdx.x;
    if (tid < T_) hb[tid] = 0;
    __syncthreads();
    const int segLo = b * seg;
    const int segHi = min(E, segLo + seg);
    const int per = (seg + STH - 1) / STH;
    const int lo = segLo + tid * per;
    const int hi = min(segHi, lo + per);
    int c[T_];
#pragma unroll
    for (int j = 0; j < T_; ++j) c[j] = 0;
    for (int i = lo; i < hi; ++i) {
        int ty = et[i];
#pragma unroll
        for (int j = 0; j < T_; ++j) c[j] += (ty == j) ? 1 : 0;
    }
#pragma unroll
    for (int j = 0; j < T_; ++j)
        if (c[j]) atomicAdd(&hb[j], c[j]);
    __syncthreads();
    if (tid < T_) hist[b * T_ + tid] = hb[tid];
}

// ---------------------------------------------------------------------------
// K2: scan over SB segment histograms (one block of SB threads).
// Also initializes the persistent-tile atomic counter.
// ---------------------------------------------------------------------------
__global__ __launch_bounds__(SB) void k_scan(int* __restrict__ hist,
                                             int* __restrict__ typeBase,
                                             int* __restrict__ typeCount,
                                             int* __restrict__ tileBase,
                                             int* __restrict__ ctr, int grid0) {
    __shared__ int sc[SB][T_ + 1];
    __shared__ int sbase[T_];
    const int tid = threadIdx.x;
#pragma unroll
    for (int j = 0; j < T_; ++j) sc[tid][j] = hist[tid * T_ + j];
    __syncthreads();
    for (int ofs = 1; ofs < SB; ofs <<= 1) {
        int v[T_];
        if (tid >= ofs) {
#pragma unroll
            for (int j = 0; j < T_; ++j) v[j] = sc[tid - ofs][j];
        }
        __syncthreads();
        if (tid >= ofs) {
#pragma unroll
            for (int j = 0; j < T_; ++j) sc[tid][j] += v[j];
        }
        __syncthreads();
    }
    if (tid == 0) {
        int b = 0, tb = 0;
#pragma unroll
        for (int j = 0; j < T_; ++j) {
            int cntj = sc[SB - 1][j];
            sbase[j] = b;
            typeBase[j] = b;
            typeCount[j] = cntj;
            tileBase[j] = tb;
            b += cntj;
            tb += (cntj + TE - 1) / TE;
        }
        tileBase[T_] = tb;
        ctr[0] = grid0;
    }
    __syncthreads();
#pragma unroll
    for (int j = 0; j < T_; ++j)
        hist[tid * T_ + j] = sbase[j] + (tid ? sc[tid - 1][j] : 0);
}

// ---------------------------------------------------------------------------
// K3: stable scatter. SB blocks x STH threads, same segmentation as K1.
// ---------------------------------------------------------------------------
__global__ __launch_bounds__(STH) void k_scatter(const int* __restrict__ et, int E, int seg,
                                                 const int* __restrict__ blockBase,
                                                 int* __restrict__ sorted_e) {
    __shared__ int sc[STH][T_ + 1];
    const int b = blockIdx.x, tid = threadIdx.x;
    const int segLo = b * seg;
    const int segHi = min(E, segLo + seg);
    const int per = (seg + STH - 1) / STH;
    const int lo = segLo + tid * per;
    const int hi = min(segHi, lo + per);
    int c[T_];
#pragma unroll
    for (int j = 0; j < T_; ++j) c[j] = 0;
    for (int i = lo; i < hi; ++i) {
        int ty = et[i];
#pragma unroll
        for (int j = 0; j < T_; ++j) c[j] += (ty == j) ? 1 : 0;
    }
#pragma unroll
    for (int j = 0; j < T_; ++j) sc[tid][j] = c[j];
    __syncthreads();
    for (int ofs = 1; ofs < STH; ofs <<= 1) {
        int v[T_];
        if (tid >= ofs) {
#pragma unroll
            for (int j = 0; j < T_; ++j) v[j] = sc[tid - ofs][j];
        }
        __syncthreads();
        if (tid >= ofs) {
#pragma unroll
            for (int j = 0; j < T_; ++j) sc[tid][j] += v[j];
        }
        __syncthreads();
    }
    int p[T_];
#pragma unroll
    for (int j = 0; j < T_; ++j)
        p[j] = blockBase[b * T_ + j] + (tid ? sc[tid - 1][j] : 0);
    for (int i = lo; i < hi; ++i) {
        int ty = et[i];
        int r = 0;
#pragma unroll
        for (int j = 0; j < T_; ++j) {
            if (ty == j) { r = p[j]; p[j] = r + 1; }
        }
        sorted_e[r] = i;
    }
}

// ---------------------------------------------------------------------------
// 16-lane butterfly fold (verified R7): lane ln ends with sum-over-lanes of
// v[ln] (identity index mapping).
// ---------------------------------------------------------------------------
__device__ __forceinline__ float fold16(float (&v)[16], int ln) {
    float v8[8];
#pragma unroll
    for (int a = 0; a < 8; ++a) {
        float keep = (ln & 1) ? v[2 * a + 1] : v[2 * a];
        float send = (ln & 1) ? v[2 * a] : v[2 * a + 1];
        v8[a] = keep + __shfl_xor(send, 1);
    }
    float v4[4];
#pragma unroll
    for (int a = 0; a < 4; ++a) {
        float keep = (ln & 2) ? v8[2 * a + 1] : v8[2 * a];
        float send = (ln & 2) ? v8[2 * a] : v8[2 * a + 1];
        v4[a] = keep + __shfl_xor(send, 2);
    }
    float v2[2];
#pragma unroll
    for (int a = 0; a < 2; ++a) {
        float keep = (ln & 4) ? v4[2 * a + 1] : v4[2 * a];
        float send = (ln & 4) ? v4[2 * a] : v4[2 * a + 1];
        v2[a] = keep + __shfl_xor(send, 4);
    }
    float keep = (ln & 8) ? v2[1] : v2[0];
    float send = (ln & 8) ? v2[0] : v2[1];
    return keep + __shfl_xor(send, 8);
}

// ---------------------------------------------------------------------------
// Main fused kernel, v9: wave specialization. 8 waves (2/SIMD); waves 0-3
// ("IO") keep ALL global traffic (gll h-staging, weight loads, h_save
// stores, W-convert) — exactly the R6/R8-proven 4-issuing-wave point.
// Waves 4-7 are LDS+MFMA only. wT double-buffered so W(ch+1) conversion
// overlaps chunk-ch MFMA -> ONE barrier per chunk. Each wave owns a-tile
// triple {w8, w8+8, w8+16} = (src,pos,neg) rows of the same 16 edges ->
// in-register relu-combine + single fold16 epilogue (P in v[0..7], N in
// v[8..15]).
// ---------------------------------------------------------------------------
__global__ __launch_bounds__(NTH, 2) void k_main(
    const float* __restrict__ h,
    const float* __restrict__ srcW, const float* __restrict__ srcB,
    const float* __restrict__ dstW, const float* __restrict__ dstB,
    const float* __restrict__ outW, const float* __restrict__ outB,
    const int* __restrict__ sorted_e,
    const int* __restrict__ typeBase, const int* __restrict__ typeCount,
    const int* __restrict__ tileBase,
    int* __restrict__ ctr,
    float* __restrict__ out, int E)
{
    const int tid = threadIdx.x;
    const int w8  = tid >> 6;          // wave 0..7
    const int l   = tid & 63;
    const int ln  = l & 15;            // A row-in-tile / B,C col
    const int lg  = l >> 4;            // k-group 0..3
    const bool isIO = tid < 256;

    __shared__ __align__(16) float4 stgH[2][3 * TE * (DC / 4)];   // 98304 B
    __shared__ __align__(16) unsigned wTu[2][4 * 4 * 112 * 4];    // 57344 B
    __shared__ int eIdx[TE];
    __shared__ int sNext;

    const int nT = tileBase[T_];
    const size_t mStride = (size_t)E * D_;
    float* const outH = out + (size_t)4 * E;

    // convert-item decomposition (IO threads): item -> (mat, lg, n)
    int cmat[4], clg[4], cnld[4], cslot[4];
    bool cok[4];
    if (isIO) {
#pragma unroll
        for (int it = 0; it < 4; ++it) {
            int item = it * 256 + tid;
            cok[it] = item < 896;
            int itc = cok[it] ? item : 0;
            cmat[it] = itc / 448;
            int rem  = itc % 448;
            clg[it]  = rem / 112;
            int cn   = rem % 112;
            cnld[it] = (cn < H_) ? cn : (H_ - 1);
            cslot[it] = cn ^ ((cn >> 3) & 7);
        }
    }

    // per-thread A geometry (all waves): rows r = w8*16+ln in each m-block
    const int rA  = w8 * 16 + ln;
    const int swA = (rA ^ (rA >> 3)) & 7;
    const int sl0 = (2 * lg) ^ swA;
    const int sl1 = (2 * lg + 1) ^ swA;

    int tile = blockIdx.x;
    while (tile < nT) {
        int t = 0;
#pragma unroll
        for (int j = 1; j < T_; ++j) t += (tile >= tileBase[j]) ? 1 : 0;
        const int i0   = (tile - tileBase[t]) * TE;
        const int cnt  = typeCount[t];
        const int base = typeBase[t];

        if (tid < TE) {
            int p = i0 + tid;
            eIdx[tid] = sorted_e[base + (p < cnt ? p : i0)];
        }
        __syncthreads();   // eIdx visible

        const float* wsBase = srcW + (size_t)t * D_ * H_;
        const float* wdBase = dstW + (size_t)t * D_ * H_;

        // ---- IO staging geometry (R6/R8-proven) ----
        const float* rowSrc[4]; float* rowHS[4]; int slotLin[4]; bool gok[4];
        if (isIO) {
            const int r0 = tid >> 3, s8 = tid & 7;
#pragma unroll
            for (int rr4 = 0; rr4 < 4; ++rr4) {
                int rr = r0 + rr4 * 32;
                int sw = (rr ^ (rr >> 3)) & 7;
                int c4 = s8 ^ sw;
                int e  = eIdx[rr];
                rowSrc[rr4]  = h    + (size_t)e * D_ + (c4 << 2);
                rowHS[rr4]   = outH + (size_t)e * D_ + (s8 << 2);
                slotLin[rr4] = rr * 8 + c4;
                gok[rr4]     = (i0 + rr) < cnt;
            }
        }

        auto stageH = [&](int buf, int d0c) {
            float4* dH = &stgH[buf][0];
#pragma unroll
            for (int m = 0; m < 3; ++m)
#pragma unroll
                for (int rr4 = 0; rr4 < 4; ++rr4)
                    __builtin_amdgcn_global_load_lds(
                        (const __attribute__((address_space(1))) void*)(rowSrc[rr4] + m * mStride + d0c),
                        (__attribute__((address_space(3))) void*)(dH + m * 1024 + rr4 * 256 + tid),
                        16, 0, 0);
        };
        auto loadW = [&](int d0c, float (&wf)[4][8]) {
#pragma unroll
            for (int it = 0; it < 4; ++it) {
                const float* wb = (cmat[it] ? wdBase : wsBase)
                                + (size_t)(d0c + clg[it] * 8) * H_ + cnld[it];
#pragma unroll
                for (int j = 0; j < 8; ++j) wf[it][j] = wb[(size_t)j * H_];
            }
        };
        auto convW = [&](int buf, const float (&wf)[4][8]) {
#pragma unroll
            for (int it = 0; it < 4; ++it) {
                if (cok[it]) {
                    unsigned hu[4], lu[4];
#pragma unroll
                    for (int p = 0; p < 4; ++p) {
                        float x0 = wf[it][2 * p], x1 = wf[it][2 * p + 1];
                        unsigned short h0 = bfhi(x0), h1 = bfhi(x1);
                        unsigned short l0 = bfhi(x0 - bfback(h0));
                        unsigned short l1 = bfhi(x1 - bfback(h1));
                        hu[p] = (unsigned)h0 | ((unsigned)h1 << 16);
                        lu[p] = (unsigned)l0 | ((unsigned)l1 << 16);
                    }
                    int bHi = (((cmat[it] * 2 + 0) * 4 + clg[it]) * 112 + cslot[it]) * 4;
                    int bLo = (((cmat[it] * 2 + 1) * 4 + clg[it]) * 112 + cslot[it]) * 4;
                    *(uint4*)&wTu[buf][bHi] = (uint4){hu[0], hu[1], hu[2], hu[3]};
                    *(uint4*)&wTu[buf][bLo] = (uint4){lu[0], lu[1], lu[2], lu[3]};
                }
            }
        };

        f32x4 acc[3][7];
#pragma unroll
        for (int s = 0; s < 3; ++s)
#pragma unroll
            for (int nt = 0; nt < 7; ++nt) acc[s][nt] = (f32x4){0.f, 0.f, 0.f, 0.f};

        // ---- per-tile prologue (IO only): stage h(0), convert W(0) ----
        if (isIO) {
            stageH(0, 0);
            float wf0[4][8];
            loadW(0, wf0);
            convW(0, wf0);
        }

#pragma unroll 1
        for (int ch = 0; ch < NC; ++ch) {
            const int d0 = ch * DC;
            const int cb = ch & 1;

            __syncthreads();   // gll(ch) landed (IO vmcnt), wT[cb] written (IO lgkm)

            const float4* csH = &stgH[cb][0];

            if (isIO) {
                const bool more = (ch + 1) < NC;
                float wf[4][8];
                if (more) loadW(d0 + DC, wf);         // oldest vm ops this chunk
                if (more) stageH(cb ^ 1, d0 + DC);    // in flight across whole chunk
                // fused h_save: de-permuted readback, ascending full-line stores
#pragma unroll
                for (int m = 0; m < 2; ++m)
#pragma unroll
                    for (int rr4 = 0; rr4 < 4; ++rr4) {
                        float4 v = csH[m * 1024 + slotLin[rr4]];
                        if (gok[rr4]) *(float4*)(rowHS[rr4] + m * mStride + d0) = v;
                    }
                if (more) convW(cb ^ 1, wf);          // wT for next chunk
            }

            // ---- all waves: A-frags (own 16 edges x 3 m-blocks) + MFMA ----
            bf16x8 Ahi[3], Alo[3];
#pragma unroll
            for (int s = 0; s < 3; ++s) {
                const float4* rp = csH + s * 1024 + rA * 8;
                float4 x0 = rp[sl0];
                float4 x1 = rp[sl1];
#pragma unroll
                for (int j = 0; j < 4; ++j) {
                    float v0 = ((const float*)&x0)[j];
                    unsigned short hh = bfhi(v0);
                    Ahi[s][j] = (short)hh;
                    Alo[s][j] = (short)bfhi(v0 - bfback(hh));
                }
#pragma unroll
                for (int j = 0; j < 4; ++j) {
                    float v1 = ((const float*)&x1)[j];
                    unsigned short hh = bfhi(v1);
                    Ahi[s][4 + j] = (short)hh;
                    Alo[s][4 + j] = (short)bfhi(v1 - bfback(hh));
                }
            }

#pragma unroll
            for (int nt = 0; nt < 7; ++nt) {
                const int n = nt * 16 + ln;
                const int slotP = n ^ ((n >> 3) & 7);
                bf16x8 B[2][2];
#pragma unroll
                for (int mat = 0; mat < 2; ++mat)
#pragma unroll
                    for (int hl = 0; hl < 2; ++hl)
                        B[mat][hl] = *(const bf16x8*)&wTu[cb][(((mat * 2 + hl) * 4 + lg) * 112 + slotP) * 4];
#pragma unroll
                for (int s = 0; s < 3; ++s) {
                    const int mm = (s == 0) ? 0 : 1;
                    acc[s][nt] = __builtin_amdgcn_mfma_f32_16x16x32_bf16(Ahi[s], B[mm][0], acc[s][nt], 0, 0, 0);
                    acc[s][nt] = __builtin_amdgcn_mfma_f32_16x16x32_bf16(Ahi[s], B[mm][1], acc[s][nt], 0, 0, 0);
                    acc[s][nt] = __builtin_amdgcn_mfma_f32_16x16x32_bf16(Alo[s], B[mm][0], acc[s][nt], 0, 0, 0);
                }
            }
        }

        // ---- epilogue: bias + relu-combine + out-layer (fold16, verified) ----
        {
            float sB7[7], dB7[7], woA[7], woB[7];
            bool valn[7];
#pragma unroll
            for (int nt = 0; nt < 7; ++nt) {
                int n = nt * 16 + ln;
                valn[nt] = (n < H_);
                int nc = valn[nt] ? n : (H_ - 1);
                sB7[nt] = srcB[t * H_ + nc];
                dB7[nt] = dstB[t * H_ + nc];
                float2 wo = *(const float2*)(outW + (size_t)t * H_ * C_ + nc * C_);
                woA[nt] = wo.x; woB[nt] = wo.y;
            }

            float v16[16];
#pragma unroll
            for (int i = 0; i < 16; ++i) v16[i] = 0.f;
#pragma unroll
            for (int nt = 0; nt < 7; ++nt)
#pragma unroll
                for (int reg = 0; reg < 4; ++reg) {
                    float sv = acc[0][nt][reg] + sB7[nt] + dB7[nt];
                    float pe = fmaxf(acc[1][nt][reg] + sv, 0.f);
                    float ne = fmaxf(acc[2][nt][reg] + sv, 0.f);
                    pe = valn[nt] ? pe : 0.f;
                    ne = valn[nt] ? ne : 0.f;
                    v16[reg * 2 + 0]     = fmaf(pe, woA[nt], v16[reg * 2 + 0]);
                    v16[reg * 2 + 1]     = fmaf(pe, woB[nt], v16[reg * 2 + 1]);
                    v16[8 + reg * 2 + 0] = fmaf(ne, woA[nt], v16[8 + reg * 2 + 0]);
                    v16[8 + reg * 2 + 1] = fmaf(ne, woB[nt], v16[8 + reg * 2 + 1]);
                }

            float tot = fold16(v16, ln);   // lane ln: idx ln = pn*8 + reg*2 + c
            const int c   = ln & 1;
            const int reg = (ln >> 1) & 3;
            const int pn  = ln >> 3;
            const int e   = w8 * 16 + lg * 4 + reg;
            if (i0 + e < cnt) {
                float val = tot + outB[t * C_ + c];
                size_t pidx = (size_t)(base + i0 + e) * C_ + c;
                out[(pn ? (size_t)C_ * E : (size_t)0) + pidx] = val;
            }
        }

        // ---- steal next tile ----
        __syncthreads();                 // all waves done with stgH/wT/eIdx
        if (tid == 0) sNext = atomicAdd(ctr, 1);
        __syncthreads();
        tile = sNext;
    }
}

// ---------------------------------------------------------------------------
extern "C" void kernel_launch(void* const* d_in, const int* in_sizes, int n_in,
                              void* d_out, int out_size, void* d_ws, size_t ws_size,
                              hipStream_t stream) {
    (void)n_in; (void)out_size; (void)ws_size;
    const float* h    = (const float*)d_in[0];
    const float* srcW = (const float*)d_in[1];
    const float* srcB = (const float*)d_in[2];
    const float* dstW = (const float*)d_in[3];
    const float* dstB = (const float*)d_in[4];
    const float* outW = (const float*)d_in[5];
    const float* outB = (const float*)d_in[6];
    const int*   et   = (const int*)d_in[7];
    const int E = in_sizes[7];

    float* out = (float*)d_out;
    int* ws = (int*)d_ws;
    int* typeBase  = ws;
    int* typeCount = ws + 8;
    int* tileBase  = ws + 16;
    int* ctr       = ws + WS_CTR;
    int* hist      = ws + WS_HIST;
    int* sorted_e  = ws + WS_SORTED;

    const int seg = (E + SB - 1) / SB;
    k_hist<<<SB, STH, 0, stream>>>(et, E, seg, hist);
    k_scan<<<1, SB, 0, stream>>>(hist, typeBase, typeCount, tileBase, ctr, GRID_MAIN);
    k_scatter<<<SB, STH, 0, stream>>>(et, E, seg, hist, sorted_e);

    k_main<<<GRID_MAIN, NTH, 0, stream>>>(h, srcW, srcB, dstW, dstB, outW, outB,
                                          sorted_e, typeBase, typeCount, tileBase,
                                          ctr, out, E);
}

// Round 10
// 1049.492 us; speedup vs baseline: 1.1178x; 1.1178x over previous
//
#include <hip/hip_runtime.h>

// Problem constants (from reference): T=8, D=512, H=100, C=2, NEG=1
constexpr int D_ = 512;
constexpr int H_ = 100;
constexpr int C_ = 2;
constexpr int T_ = 8;

constexpr int TE  = 128;        // edges per tile
constexpr int DC  = 32;         // D-chunk (floats) = one 128B line per row = one MFMA K
constexpr int NC  = D_ / DC;    // 16 chunks
constexpr int NTH = 256;        // 4 waves: the proven fastest + traffic-safe point (R8)
constexpr int GRID_MAIN = 256;  // persistent: one block per CU
constexpr int SB  = 128;        // sort segments / blocks
constexpr int STH = 256;        // threads per sort block

// ws ints: [0:8) typeBase | [8:16) typeCount | [16:25) tileBase | [26] tile ctr
//          [32:32+SB*8) hist/blockBase | [1056:1056+E) sorted_e
//          [131072 ...) wPre: preconverted weights, 8t x 16ch x 7168 dwords
constexpr int WS_CTR  = 26;
constexpr int WS_HIST = 32;
constexpr int WS_SORTED = 32 + SB * T_;   // 1056
constexpr int WS_WPRE = 131072;           // 512 KB offset; wPre = 3.67 MB

typedef __attribute__((ext_vector_type(8))) short bf16x8;
typedef __attribute__((ext_vector_type(4))) float f32x4;

__device__ __forceinline__ unsigned short bfhi(float x) {
    return (unsigned short)(__builtin_bit_cast(unsigned int, x) >> 16);
}
__device__ __forceinline__ float bfback(unsigned short u) {
    return __builtin_bit_cast(float, (unsigned int)u << 16);
}

// ---------------------------------------------------------------------------
// K1: per-segment histogram. SB blocks x STH threads.
// ---------------------------------------------------------------------------
__global__ __launch_bounds__(STH) void k_hist(const int* __restrict__ et, int E, int seg,
                                              int* __restrict__ hist) {
    __shared__ int hb[T_];
    const int b = blockIdx.x, tid = threadIdx.x;
    if (tid < T_) hb[tid] = 0;
    __syncthreads();
    const int segLo = b * seg;
    const int segHi = min(E, segLo + seg);
    const int per = (seg + STH - 1) / STH;
    const int lo = segLo + tid * per;
    const int hi = min(segHi, lo + per);
    int c[T_];
#pragma unroll
    for (int j = 0; j < T_; ++j) c[j] = 0;
    for (int i = lo; i < hi; ++i) {
        int ty = et[i];
#pragma unroll
        for (int j = 0; j < T_; ++j) c[j] += (ty == j) ? 1 : 0;
    }
#pragma unroll
    for (int j = 0; j < T_; ++j)
        if (c[j]) atomicAdd(&hb[j], c[j]);
    __syncthreads();
    if (tid < T_) hist[b * T_ + tid] = hb[tid];
}

// ---------------------------------------------------------------------------
// K2: scan over SB segment histograms; also inits the tile-steal counter.
// ---------------------------------------------------------------------------
__global__ __launch_bounds__(SB) void k_scan(int* __restrict__ hist,
                                             int* __restrict__ typeBase,
                                             int* __restrict__ typeCount,
                                             int* __restrict__ tileBase,
                                             int* __restrict__ ctr, int grid0) {
    __shared__ int sc[SB][T_ + 1];
    __shared__ int sbase[T_];
    const int tid = threadIdx.x;
#pragma unroll
    for (int j = 0; j < T_; ++j) sc[tid][j] = hist[tid * T_ + j];
    __syncthreads();
    for (int ofs = 1; ofs < SB; ofs <<= 1) {
        int v[T_];
        if (tid >= ofs) {
#pragma unroll
            for (int j = 0; j < T_; ++j) v[j] = sc[tid - ofs][j];
        }
        __syncthreads();
        if (tid >= ofs) {
#pragma unroll
            for (int j = 0; j < T_; ++j) sc[tid][j] += v[j];
        }
        __syncthreads();
    }
    if (tid == 0) {
        int b = 0, tb = 0;
#pragma unroll
        for (int j = 0; j < T_; ++j) {
            int cntj = sc[SB - 1][j];
            sbase[j] = b;
            typeBase[j] = b;
            typeCount[j] = cntj;
            tileBase[j] = tb;
            b += cntj;
            tb += (cntj + TE - 1) / TE;
        }
        tileBase[T_] = tb;
        ctr[0] = grid0;
    }
    __syncthreads();
#pragma unroll
    for (int j = 0; j < T_; ++j)
        hist[tid * T_ + j] = sbase[j] + (tid ? sc[tid - 1][j] : 0);
}

// ---------------------------------------------------------------------------
// K3: stable scatter. SB blocks x STH threads, same segmentation as K1.
// ---------------------------------------------------------------------------
__global__ __launch_bounds__(STH) void k_scatter(const int* __restrict__ et, int E, int seg,
                                                 const int* __restrict__ blockBase,
                                                 int* __restrict__ sorted_e) {
    __shared__ int sc[STH][T_ + 1];
    const int b = blockIdx.x, tid = threadIdx.x;
    const int segLo = b * seg;
    const int segHi = min(E, segLo + seg);
    const int per = (seg + STH - 1) / STH;
    const int lo = segLo + tid * per;
    const int hi = min(segHi, lo + per);
    int c[T_];
#pragma unroll
    for (int j = 0; j < T_; ++j) c[j] = 0;
    for (int i = lo; i < hi; ++i) {
        int ty = et[i];
#pragma unroll
        for (int j = 0; j < T_; ++j) c[j] += (ty == j) ? 1 : 0;
    }
#pragma unroll
    for (int j = 0; j < T_; ++j) sc[tid][j] = c[j];
    __syncthreads();
    for (int ofs = 1; ofs < STH; ofs <<= 1) {
        int v[T_];
        if (tid >= ofs) {
#pragma unroll
            for (int j = 0; j < T_; ++j) v[j] = sc[tid - ofs][j];
        }
        __syncthreads();
        if (tid >= ofs) {
#pragma unroll
            for (int j = 0; j < T_; ++j) sc[tid][j] += v[j];
        }
        __syncthreads();
    }
    int p[T_];
#pragma unroll
    for (int j = 0; j < T_; ++j)
        p[j] = blockBase[b * T_ + j] + (tid ? sc[tid - 1][j] : 0);
    for (int i = lo; i < hi; ++i) {
        int ty = et[i];
        int r = 0;
#pragma unroll
        for (int j = 0; j < T_; ++j) {
            if (ty == j) { r = p[j]; p[j] = r + 1; }
        }
        sorted_e[r] = i;
    }
}

// ---------------------------------------------------------------------------
// K4: one-time weight preconversion. fp32 W[t][mat][d][n] -> split-bf16
// hi/lo, transposed + padded + XOR-slot-swizzled, stored per (t, chunk) as
// the exact 28,672B LDS image k_main streams in:
//   wPre dword[(t*16+ch)*7168 + ((mat*2+hl)*4+lg)*448 + slot(n)*4 + q]
//   = bf16(W[d=ch*32+lg*8+2q][n]) | bf16(W[d+1][n])<<16,  slot = n^((n>>3)&7)
// Layout identical to R9's measured-zero-conflict wTu.
// Grid: 448 x 256 = 114,688 = 8t*16ch*8(mat,lg)*112n threads, one per (..n).
// ---------------------------------------------------------------------------
__global__ __launch_bounds__(256) void k_prew(const float* __restrict__ srcW,
                                              const float* __restrict__ dstW,
                                              unsigned* __restrict__ wPre) {
    const int flat = blockIdx.x * 256 + threadIdx.x;
    const int n    = flat % 112;
    int rest = flat / 112;
    const int lgm = rest % 8;
    const int mat = lgm >> 2, lg = lgm & 3;
    rest /= 8;
    const int ch = rest % 16, t = rest / 16;

    float x[8];
    if (n < H_) {
        const float* W = (mat ? dstW : srcW) + (size_t)t * D_ * H_
                       + (size_t)(ch * 32 + lg * 8) * H_ + n;
#pragma unroll
        for (int j = 0; j < 8; ++j) x[j] = W[(size_t)j * H_];
    } else {
#pragma unroll
        for (int j = 0; j < 8; ++j) x[j] = 0.f;
    }
    unsigned hu[4], lu[4];
#pragma unroll
    for (int p = 0; p < 4; ++p) {
        float x0 = x[2 * p], x1 = x[2 * p + 1];
        unsigned short h0 = bfhi(x0), h1 = bfhi(x1);
        unsigned short l0 = bfhi(x0 - bfback(h0));
        unsigned short l1 = bfhi(x1 - bfback(h1));
        hu[p] = (unsigned)h0 | ((unsigned)h1 << 16);
        lu[p] = (unsigned)l0 | ((unsigned)l1 << 16);
    }
    const int slot = n ^ ((n >> 3) & 7);
    const unsigned bse = (unsigned)(t * 16 + ch) * 7168u;
    unsigned hiA = bse + (unsigned)(((mat * 2 + 0) * 4 + lg) * 448 + slot * 4);
    unsigned loA = bse + (unsigned)(((mat * 2 + 1) * 4 + lg) * 448 + slot * 4);
    *(uint4*)&wPre[hiA] = (uint4){hu[0], hu[1], hu[2], hu[3]};
    *(uint4*)&wPre[loA] = (uint4){lu[0], lu[1], lu[2], lu[3]};
}

// ---------------------------------------------------------------------------
// 16-lane butterfly fold (verified R7/R8).
// ---------------------------------------------------------------------------
__device__ __forceinline__ float fold16(float (&v)[16], int ln) {
    float v8[8];
#pragma unroll
    for (int a = 0; a < 8; ++a) {
        float keep = (ln & 1) ? v[2 * a + 1] : v[2 * a];
        float send = (ln & 1) ? v[2 * a] : v[2 * a + 1];
        v8[a] = keep + __shfl_xor(send, 1);
    }
    float v4[4];
#pragma unroll
    for (int a = 0; a < 4; ++a) {
        float keep = (ln & 2) ? v8[2 * a + 1] : v8[2 * a];
        float send = (ln & 2) ? v8[2 * a] : v8[2 * a + 1];
        v4[a] = keep + __shfl_xor(send, 2);
    }
    float v2[2];
#pragma unroll
    for (int a = 0; a < 2; ++a) {
        float keep = (ln & 4) ? v4[2 * a + 1] : v4[2 * a];
        float send = (ln & 4) ? v4[2 * a] : v4[2 * a + 1];
        v2[a] = keep + __shfl_xor(send, 4);
    }
    float keep = (ln & 8) ? v2[1] : v2[0];
    float send = (ln & 8) ? v2[0] : v2[1];
    return keep + __shfl_xor(send, 8);
}

// ---------------------------------------------------------------------------
// Main fused kernel, v10 = R8's 4-wave structure with the per-chunk weight
// path (32 scalar loads + convert + lgkm barrier) replaced by 7 gll ops
// streaming the preconverted 28.7KB LDS image from wPre. Per chunk: ONE
// barrier; the only intra-chunk waits are LDS (ds_read for A/B); all 19
// gll ops (h + W for ch+1) stay in flight across the whole chunk.
// ---------------------------------------------------------------------------
__global__ __launch_bounds__(NTH, 1) void k_main(
    const float* __restrict__ h,
    const float* __restrict__ srcB, const float* __restrict__ dstB,
    const float* __restrict__ outW, const float* __restrict__ outB,
    const int* __restrict__ sorted_e,
    const int* __restrict__ typeBase, const int* __restrict__ typeCount,
    const int* __restrict__ tileBase,
    const unsigned* __restrict__ wPre,
    int* __restrict__ ctr,
    float* __restrict__ out, int E)
{
    const int tid = threadIdx.x;
    const int w   = tid >> 6;          // wave 0..3
    const int l   = tid & 63;
    const int ln  = l & 15;            // A row-in-tile / B,C col
    const int lg  = l >> 4;            // k-group 0..3

    __shared__ __align__(16) float4 stgH[2][3 * TE * (DC / 4)];   // 98304 B
    __shared__ __align__(16) unsigned wB[2][7168];                // 57344 B
    __shared__ int eIdx[TE];
    __shared__ int sNext;

    const int nT = tileBase[T_];
    const size_t mStride = (size_t)E * D_;
    float* const outH = out + (size_t)4 * E;

    int tile = blockIdx.x;
    while (tile < nT) {
        int t = 0;
#pragma unroll
        for (int j = 1; j < T_; ++j) t += (tile >= tileBase[j]) ? 1 : 0;
        const int i0   = (tile - tileBase[t]) * TE;
        const int cnt  = typeCount[t];
        const int base = typeBase[t];

        if (tid < TE) {
            int p = i0 + tid;
            eIdx[tid] = sorted_e[base + (p < cnt ? p : i0)];
        }
        __syncthreads();   // eIdx visible

        // ---- h staging geometry (R6/R8-proven) ----
        const int r0 = tid >> 3, s8 = tid & 7;
        const float* rowSrc[4]; float* rowHS[4]; int slotLin[4]; bool gok[4];
#pragma unroll
        for (int rr4 = 0; rr4 < 4; ++rr4) {
            int rr = r0 + rr4 * 32;
            int sw = (rr ^ (rr >> 3)) & 7;
            int c4 = s8 ^ sw;
            int e  = eIdx[rr];
            rowSrc[rr4]  = h    + (size_t)e * D_ + (c4 << 2);
            rowHS[rr4]   = outH + (size_t)e * D_ + (s8 << 2);
            slotLin[rr4] = rr * 8 + c4;
            gok[rr4]     = (i0 + rr) < cnt;
        }

        const float4* const wPreT = (const float4*)(wPre + (size_t)t * 16 * 7168);

        auto stageH = [&](int buf, int d0c) {
            float4* dH = &stgH[buf][0];
#pragma unroll
            for (int m = 0; m < 3; ++m)
#pragma unroll
                for (int rr4 = 0; rr4 < 4; ++rr4)
                    __builtin_amdgcn_global_load_lds(
                        (const __attribute__((address_space(1))) void*)(rowSrc[rr4] + m * mStride + d0c),
                        (__attribute__((address_space(3))) void*)(dH + m * 1024 + rr4 * 256 + tid),
                        16, 0, 0);
        };
        auto stageW = [&](int buf, int chl) {
            const float4* src = wPreT + chl * 1792;
            float4* dst = (float4*)&wB[buf][0];
#pragma unroll
            for (int it = 0; it < 7; ++it)
                __builtin_amdgcn_global_load_lds(
                    (const __attribute__((address_space(1))) void*)(src + it * 256 + tid),
                    (__attribute__((address_space(3))) void*)(dst + it * 256 + tid),
                    16, 0, 0);
        };

        f32x4 acc[6][7];
#pragma unroll
        for (int a = 0; a < 6; ++a)
#pragma unroll
            for (int nt = 0; nt < 7; ++nt) acc[a][nt] = (f32x4){0.f, 0.f, 0.f, 0.f};

        stageH(0, 0);
        stageW(0, 0);

#pragma unroll 1
        for (int ch = 0; ch < NC; ++ch) {
            const int d0 = ch * DC;
            const int cb = ch & 1;

            __syncthreads();   // gll(ch) landed (h + W); all waves done ch-1

            if (ch + 1 < NC) {
                stageH(cb ^ 1, d0 + DC);    // in flight across the whole chunk
                stageW(cb ^ 1, ch + 1);
            }

            const float4* csH = &stgH[cb][0];

            // fused h_save: de-permuted readback, ascending full-line stores
#pragma unroll
            for (int m = 0; m < 2; ++m)
#pragma unroll
                for (int rr4 = 0; rr4 < 4; ++rr4) {
                    float4 v = csH[m * 1024 + slotLin[rr4]];
                    if (gok[rr4]) *(float4*)(rowHS[rr4] + m * mStride + d0) = v;
                }

            // A fragments: read fp32 h LDS (swizzled slots), split to bf16 hi/lo
            bf16x8 Ahi[6], Alo[6];
#pragma unroll
            for (int a = 0; a < 6; ++a) {
                const int row = (w + 4 * a) * 16 + ln;
                const int swR = (row ^ (row >> 3)) & 7;
                const float4* rp = csH + row * 8;
                float4 x0 = rp[(2 * lg) ^ swR];
                float4 x1 = rp[(2 * lg + 1) ^ swR];
#pragma unroll
                for (int j = 0; j < 4; ++j) {
                    float v0 = ((const float*)&x0)[j];
                    unsigned short hh = bfhi(v0);
                    Ahi[a][j] = (short)hh;
                    Alo[a][j] = (short)bfhi(v0 - bfback(hh));
                }
#pragma unroll
                for (int j = 0; j < 4; ++j) {
                    float v1 = ((const float*)&x1)[j];
                    unsigned short hh = bfhi(v1);
                    Ahi[a][4 + j] = (short)hh;
                    Alo[a][4 + j] = (short)bfhi(v1 - bfback(hh));
                }
            }

            // MFMA: B-frags from wB[cb] (R9's zero-conflict layout)
#pragma unroll
            for (int nt = 0; nt < 7; ++nt) {
                const int n = nt * 16 + ln;
                const int slotP = n ^ ((n >> 3) & 7);
                bf16x8 B[2][2];
#pragma unroll
                for (int mat = 0; mat < 2; ++mat)
#pragma unroll
                    for (int hl = 0; hl < 2; ++hl)
                        B[mat][hl] = *(const bf16x8*)&wB[cb][(((mat * 2 + hl) * 4 + lg) * 112 + slotP) * 4];
#pragma unroll
                for (int a = 0; a < 6; ++a) {
                    const int mm = (a < 2) ? 0 : 1;
                    acc[a][nt] = __builtin_amdgcn_mfma_f32_16x16x32_bf16(Ahi[a], B[mm][0], acc[a][nt], 0, 0, 0);
                    acc[a][nt] = __builtin_amdgcn_mfma_f32_16x16x32_bf16(Ahi[a], B[mm][1], acc[a][nt], 0, 0, 0);
                    acc[a][nt] = __builtin_amdgcn_mfma_f32_16x16x32_bf16(Alo[a], B[mm][0], acc[a][nt], 0, 0, 0);
                }
            }
        }

        // ---- epilogue: bias + relu-combine + out-layer (verified R7/R8) ----
        float sB7[7], dB7[7], woA[7], woB[7];
        bool valn[7];
#pragma unroll
        for (int nt = 0; nt < 7; ++nt) {
            int n = nt * 16 + ln;
            valn[nt] = (n < H_);
            int nc = valn[nt] ? n : (H_ - 1);
            sB7[nt] = srcB[t * H_ + nc];
            dB7[nt] = dstB[t * H_ + nc];
            float2 wo = *(const float2*)(outW + (size_t)t * H_ * C_ + nc * C_);
            woA[nt] = wo.x; woB[nt] = wo.y;
        }

        float pp[16], nn[16];
#pragma unroll
        for (int i = 0; i < 16; ++i) { pp[i] = 0.f; nn[i] = 0.f; }
#pragma unroll
        for (int nt = 0; nt < 7; ++nt)
#pragma unroll
            for (int a = 0; a < 2; ++a)
#pragma unroll
                for (int reg = 0; reg < 4; ++reg) {
                    float sv = acc[a][nt][reg] + sB7[nt] + dB7[nt];
                    float pe = fmaxf(acc[a + 2][nt][reg] + sv, 0.f);
                    float ne = fmaxf(acc[a + 4][nt][reg] + sv, 0.f);
                    pe = valn[nt] ? pe : 0.f;
                    ne = valn[nt] ? ne : 0.f;
                    const int ix = a * 8 + reg * 2;
                    pp[ix]     = fmaf(pe, woA[nt], pp[ix]);
                    pp[ix + 1] = fmaf(pe, woB[nt], pp[ix + 1]);
                    nn[ix]     = fmaf(ne, woA[nt], nn[ix]);
                    nn[ix + 1] = fmaf(ne, woB[nt], nn[ix + 1]);
                }

        float totP = fold16(pp, ln);
        float totN = fold16(nn, ln);
        {
            const int c   = ln & 1;
            const int reg = (ln >> 1) & 3;
            const int aa  = (ln >> 3) & 1;
            const int e   = (w + 4 * aa) * 16 + lg * 4 + reg;
            if (i0 + e < cnt) {
                float ob = outB[t * C_ + c];
                size_t pidx = (size_t)(base + i0 + e) * C_ + c;
                out[pidx] = totP + ob;
                out[(size_t)C_ * E + pidx] = totN + ob;
            }
        }

        // ---- steal next tile ----
        __syncthreads();
        if (tid == 0) sNext = atomicAdd(ctr, 1);
        __syncthreads();
        tile = sNext;
    }
}

// ---------------------------------------------------------------------------
extern "C" void kernel_launch(void* const* d_in, const int* in_sizes, int n_in,
                              void* d_out, int out_size, void* d_ws, size_t ws_size,
                              hipStream_t stream) {
    (void)n_in; (void)out_size; (void)ws_size;
    const float* h    = (const float*)d_in[0];
    const float* srcW = (const float*)d_in[1];
    const float* srcB = (const float*)d_in[2];
    const float* dstW = (const float*)d_in[3];
    const float* dstB = (const float*)d_in[4];
    const float* outW = (const float*)d_in[5];
    const float* outB = (const float*)d_in[6];
    const int*   et   = (const int*)d_in[7];
    const int E = in_sizes[7];

    float* out = (float*)d_out;
    int* ws = (int*)d_ws;
    int* typeBase  = ws;
    int* typeCount = ws + 8;
    int* tileBase  = ws + 16;
    int* ctr       = ws + WS_CTR;
    int* hist      = ws + WS_HIST;
    int* sorted_e  = ws + WS_SORTED;
    unsigned* wPre = (unsigned*)(ws + WS_WPRE);

    const int seg = (E + SB - 1) / SB;
    k_hist<<<SB, STH, 0, stream>>>(et, E, seg, hist);
    k_scan<<<1, SB, 0, stream>>>(hist, typeBase, typeCount, tileBase, ctr, GRID_MAIN);
    k_scatter<<<SB, STH, 0, stream>>>(et, E, seg, hist, sorted_e);
    k_prew<<<448, 256, 0, stream>>>(srcW, dstW, wPre);

    k_main<<<GRID_MAIN, NTH, 0, stream>>>(h, srcB, dstB, outW, outB,
                                          sorted_e, typeBase, typeCount, tileBase,
                                          wPre, ctr, out, E);
}

// Round 11
// 1035.668 us; speedup vs baseline: 1.1327x; 1.0133x over previous
//
#include <hip/hip_runtime.h>

// Problem constants (from reference): T=8, D=512, H=100, C=2, NEG=1
constexpr int D_ = 512;
constexpr int H_ = 100;
constexpr int C_ = 2;
constexpr int T_ = 8;

constexpr int TE  = 64;         // edges per tile
constexpr int DC  = 64;         // D-chunk (floats) = 256B per row per chunk
constexpr int NC  = D_ / DC;    // 8 chunks (16 K=32 ksteps)
constexpr int NTH = 256;        // 4 waves: traffic-safe + proven-fastest point
constexpr int GRID_MAIN = 256;  // persistent: one block per CU
constexpr int SB  = 128;        // sort segments / blocks
constexpr int STH = 256;        // threads per sort block

// ws ints: [0:8) typeBase | [8:16) typeCount | [16:25) tileBase | [26] tile ctr
//          [32:32+SB*8) hist/blockBase | [1056:1056+E) sorted_e
//          [131072 ...) wPre: preconverted weights, 8t x 16slice x 7168 dwords
constexpr int WS_CTR  = 26;
constexpr int WS_HIST = 32;
constexpr int WS_SORTED = 32 + SB * T_;   // 1056
constexpr int WS_WPRE = 131072;           // 512 KB offset; wPre = 3.67 MB

typedef __attribute__((ext_vector_type(8))) short bf16x8;
typedef __attribute__((ext_vector_type(4))) float f32x4;

__device__ __forceinline__ unsigned short bfhi(float x) {
    return (unsigned short)(__builtin_bit_cast(unsigned int, x) >> 16);
}
__device__ __forceinline__ float bfback(unsigned short u) {
    return __builtin_bit_cast(float, (unsigned int)u << 16);
}
__device__ __forceinline__ int swz16(int r) { return (r ^ (r >> 3)) & 15; }

// Counted-vmcnt barrier: waits all but the N newest vmem ops, then syncs.
// sched_barrier(0) fences compiler reordering past the asm (rule 18).
#define KBAR(NSTR) do { \
    asm volatile("s_waitcnt vmcnt(" NSTR ") lgkmcnt(0)\n\ts_barrier" ::: "memory"); \
    __builtin_amdgcn_sched_barrier(0); \
} while (0)

// ---------------------------------------------------------------------------
// K1: per-segment histogram. SB blocks x STH threads.
// ---------------------------------------------------------------------------
__global__ __launch_bounds__(STH) void k_hist(const int* __restrict__ et, int E, int seg,
                                              int* __restrict__ hist) {
    __shared__ int hb[T_];
    const int b = blockIdx.x, tid = threadIdx.x;
    if (tid < T_) hb[tid] = 0;
    __syncthreads();
    const int segLo = b * seg;
    const int segHi = min(E, segLo + seg);
    const int per = (seg + STH - 1) / STH;
    const int lo = segLo + tid * per;
    const int hi = min(segHi, lo + per);
    int c[T_];
#pragma unroll
    for (int j = 0; j < T_; ++j) c[j] = 0;
    for (int i = lo; i < hi; ++i) {
        int ty = et[i];
#pragma unroll
        for (int j = 0; j < T_; ++j) c[j] += (ty == j) ? 1 : 0;
    }
#pragma unroll
    for (int j = 0; j < T_; ++j)
        if (c[j]) atomicAdd(&hb[j], c[j]);
    __syncthreads();
    if (tid < T_) hist[b * T_ + tid] = hb[tid];
}

// ---------------------------------------------------------------------------
// K2: scan over SB segment histograms; also inits the tile-steal counter.
// ---------------------------------------------------------------------------
__global__ __launch_bounds__(SB) void k_scan(int* __restrict__ hist,
                                             int* __restrict__ typeBase,
                                             int* __restrict__ typeCount,
                                             int* __restrict__ tileBase,
                                             int* __restrict__ ctr, int grid0) {
    __shared__ int sc[SB][T_ + 1];
    __shared__ int sbase[T_];
    const int tid = threadIdx.x;
#pragma unroll
    for (int j = 0; j < T_; ++j) sc[tid][j] = hist[tid * T_ + j];
    __syncthreads();
    for (int ofs = 1; ofs < SB; ofs <<= 1) {
        int v[T_];
        if (tid >= ofs) {
#pragma unroll
            for (int j = 0; j < T_; ++j) v[j] = sc[tid - ofs][j];
        }
        __syncthreads();
        if (tid >= ofs) {
#pragma unroll
            for (int j = 0; j < T_; ++j) sc[tid][j] += v[j];
        }
        __syncthreads();
    }
    if (tid == 0) {
        int b = 0, tb = 0;
#pragma unroll
        for (int j = 0; j < T_; ++j) {
            int cntj = sc[SB - 1][j];
            sbase[j] = b;
            typeBase[j] = b;
            typeCount[j] = cntj;
            tileBase[j] = tb;
            b += cntj;
            tb += (cntj + TE - 1) / TE;
        }
        tileBase[T_] = tb;
        ctr[0] = grid0;
    }
    __syncthreads();
#pragma unroll
    for (int j = 0; j < T_; ++j)
        hist[tid * T_ + j] = sbase[j] + (tid ? sc[tid - 1][j] : 0);
}

// ---------------------------------------------------------------------------
// K3: stable scatter. SB blocks x STH threads, same segmentation as K1.
// ---------------------------------------------------------------------------
__global__ __launch_bounds__(STH) void k_scatter(const int* __restrict__ et, int E, int seg,
                                                 const int* __restrict__ blockBase,
                                                 int* __restrict__ sorted_e) {
    __shared__ int sc[STH][T_ + 1];
    const int b = blockIdx.x, tid = threadIdx.x;
    const int segLo = b * seg;
    const int segHi = min(E, segLo + seg);
    const int per = (seg + STH - 1) / STH;
    const int lo = segLo + tid * per;
    const int hi = min(segHi, lo + per);
    int c[T_];
#pragma unroll
    for (int j = 0; j < T_; ++j) c[j] = 0;
    for (int i = lo; i < hi; ++i) {
        int ty = et[i];
#pragma unroll
        for (int j = 0; j < T_; ++j) c[j] += (ty == j) ? 1 : 0;
    }
#pragma unroll
    for (int j = 0; j < T_; ++j) sc[tid][j] = c[j];
    __syncthreads();
    for (int ofs = 1; ofs < STH; ofs <<= 1) {
        int v[T_];
        if (tid >= ofs) {
#pragma unroll
            for (int j = 0; j < T_; ++j) v[j] = sc[tid - ofs][j];
        }
        __syncthreads();
        if (tid >= ofs) {
#pragma unroll
            for (int j = 0; j < T_; ++j) sc[tid][j] += v[j];
        }
        __syncthreads();
    }
    int p[T_];
#pragma unroll
    for (int j = 0; j < T_; ++j)
        p[j] = blockBase[b * T_ + j] + (tid ? sc[tid - 1][j] : 0);
    for (int i = lo; i < hi; ++i) {
        int ty = et[i];
        int r = 0;
#pragma unroll
        for (int j = 0; j < T_; ++j) {
            if (ty == j) { r = p[j]; p[j] = r + 1; }
        }
        sorted_e[r] = i;
    }
}

// ---------------------------------------------------------------------------
// K4: one-time weight preconversion (UNCHANGED from R10 — slice = K=32).
//   wPre dword[(t*16+s)*7168 + ((mat*2+hl)*4+lg)*448 + slot(n)*4 + q]
//   slot = n ^ ((n>>3)&7)
// ---------------------------------------------------------------------------
__global__ __launch_bounds__(256) void k_prew(const float* __restrict__ srcW,
                                              const float* __restrict__ dstW,
                                              unsigned* __restrict__ wPre) {
    const int flat = blockIdx.x * 256 + threadIdx.x;
    const int n    = flat % 112;
    int rest = flat / 112;
    const int lgm = rest % 8;
    const int mat = lgm >> 2, lg = lgm & 3;
    rest /= 8;
    const int s = rest % 16, t = rest / 16;

    float x[8];
    if (n < H_) {
        const float* W = (mat ? dstW : srcW) + (size_t)t * D_ * H_
                       + (size_t)(s * 32 + lg * 8) * H_ + n;
#pragma unroll
        for (int j = 0; j < 8; ++j) x[j] = W[(size_t)j * H_];
    } else {
#pragma unroll
        for (int j = 0; j < 8; ++j) x[j] = 0.f;
    }
    unsigned hu[4], lu[4];
#pragma unroll
    for (int p = 0; p < 4; ++p) {
        float x0 = x[2 * p], x1 = x[2 * p + 1];
        unsigned short h0 = bfhi(x0), h1 = bfhi(x1);
        unsigned short l0 = bfhi(x0 - bfback(h0));
        unsigned short l1 = bfhi(x1 - bfback(h1));
        hu[p] = (unsigned)h0 | ((unsigned)h1 << 16);
        lu[p] = (unsigned)l0 | ((unsigned)l1 << 16);
    }
    const int slot = n ^ ((n >> 3) & 7);
    const unsigned bse = (unsigned)(t * 16 + s) * 7168u;
    unsigned hiA = bse + (unsigned)(((mat * 2 + 0) * 4 + lg) * 448 + slot * 4);
    unsigned loA = bse + (unsigned)(((mat * 2 + 1) * 4 + lg) * 448 + slot * 4);
    *(uint4*)&wPre[hiA] = (uint4){hu[0], hu[1], hu[2], hu[3]};
    *(uint4*)&wPre[loA] = (uint4){lu[0], lu[1], lu[2], lu[3]};
}

// ---------------------------------------------------------------------------
// 16-lane butterfly fold (verified R7/R8/R9).
// ---------------------------------------------------------------------------
__device__ __forceinline__ float fold16(float (&v)[16], int ln) {
    float v8[8];
#pragma unroll
    for (int a = 0; a < 8; ++a) {
        float keep = (ln & 1) ? v[2 * a + 1] : v[2 * a];
        float send = (ln & 1) ? v[2 * a] : v[2 * a + 1];
        v8[a] = keep + __shfl_xor(send, 1);
    }
    float v4[4];
#pragma unroll
    for (int a = 0; a < 4; ++a) {
        float keep = (ln & 2) ? v8[2 * a + 1] : v8[2 * a];
        float send = (ln & 2) ? v8[2 * a] : v8[2 * a + 1];
        v4[a] = keep + __shfl_xor(send, 2);
    }
    float v2[2];
#pragma unroll
    for (int a = 0; a < 2; ++a) {
        float keep = (ln & 4) ? v4[2 * a + 1] : v4[2 * a];
        float send = (ln & 4) ? v4[2 * a] : v4[2 * a + 1];
        v2[a] = keep + __shfl_xor(send, 4);
    }
    float keep = (ln & 8) ? v2[1] : v2[0];
    float send = (ln & 8) ? v2[0] : v2[1];
    return keep + __shfl_xor(send, 8);
}

// ---------------------------------------------------------------------------
// Main fused kernel, v11: TE=64/DC=64 -> every h read and h_save write is a
// 256B contiguous run per 16-lane group (vs 128B random granules, the
// measured ~30%-efficiency DRAM regime of R6-R10). Weight slices stay K=32,
// ping-ponged per kstep from wPre (L2-hot). Per-kstep barriers use COUNTED
// vmcnt so the 1-chunk-deep h prefetch and the h_save stores stay in flight
// across barriers; only weight slices (L2 latency) ride a vmcnt(0).
// h_save stores are UNCONDITIONAL (padded rows duplicate-write identical
// bytes) so per-wave vmcnt counts are exact.
// Per-thread vmem issue order per chunk ch (even kstep): Lw(2ch+1)[7] ->
// Lh(ch+1)[12] -> stores[8]; (odd kstep): Lw(2ch+2)[7].
//   mid-chunk barrier: vmcnt(20) (last chunk: 8) -> waits Lw only
//   end-of-chunk barrier: vmcnt(0) -> waits Lh(ch+1) + Lw (both needed)
// ---------------------------------------------------------------------------
__global__ __launch_bounds__(NTH, 1) void k_main(
    const float* __restrict__ h,
    const float* __restrict__ srcB, const float* __restrict__ dstB,
    const float* __restrict__ outW, const float* __restrict__ outB,
    const int* __restrict__ sorted_e,
    const int* __restrict__ typeBase, const int* __restrict__ typeCount,
    const int* __restrict__ tileBase,
    const unsigned* __restrict__ wPre,
    int* __restrict__ ctr,
    float* __restrict__ out, int E)
{
    const int tid = threadIdx.x;
    const int w   = tid >> 6;          // wave 0..3
    const int l   = tid & 63;
    const int ln  = l & 15;            // A row-in-tile / B,C col
    const int lg  = l >> 4;            // k-group 0..3

    __shared__ __align__(16) float4 stgH[2][3 * TE * (DC / 4)];   // 2 x 49152 B
    __shared__ __align__(16) unsigned wB[2][7168];                // 2 x 28672 B
    __shared__ int eIdx[TE];
    __shared__ int sNext;

    const int nT = tileBase[T_];
    const size_t mStride = (size_t)E * D_;   // floats between m-blocks of h
    float* const outH = out + (size_t)4 * E;

    // A-frag geometry (per wave): row rA within each m-block
    const int rA = w * 16 + ln;
    const int Sa = swz16(rA);
    const int aBase = rA * 16;

    int tile = blockIdx.x;
    while (tile < nT) {
        int t = 0;
#pragma unroll
        for (int j = 1; j < T_; ++j) t += (tile >= tileBase[j]) ? 1 : 0;
        const int i0   = (tile - tileBase[t]) * TE;
        const int cnt  = typeCount[t];
        const int base = typeBase[t];

        if (tid < TE) {
            int p = i0 + tid;
            eIdx[tid] = sorted_e[base + (p < cnt ? p : i0)];
        }
        __syncthreads();   // eIdx visible (full drain once per tile: fine)

        // ---- staging geometry: 16 threads/row, 4 row-groups, 3 m-blocks ----
        const int rT  = tid >> 4;          // 0..15: row within group
        const int s16 = tid & 15;          // f4 slot (linear column)
        const float* rowS4[4];             // swizzled-col h source per rowgroup
        float*       rowH4[4];             // ascending-col h_save dest per rowgroup
        int          slotL4[4];            // LDS f4 index (readback, m=0 base)
#pragma unroll
        for (int rg = 0; rg < 4; ++rg) {
            int r  = rg * 16 + rT;
            int S  = swz16(r);
            int c16 = s16 ^ S;
            int e  = eIdx[r];
            rowS4[rg]  = h    + (size_t)e * D_ + (c16 << 2);
            rowH4[rg]  = outH + (size_t)e * D_ + (s16 << 2);
            slotL4[rg] = r * 16 + c16;     // slot holding linear col s16
        }

        const float4* const wPreT = (const float4*)(wPre + (size_t)t * 16 * 7168);

        auto stageH = [&](int buf, int d0c) {
            float4* dH = &stgH[buf][0];
#pragma unroll
            for (int m = 0; m < 3; ++m)
#pragma unroll
                for (int rg = 0; rg < 4; ++rg)
                    __builtin_amdgcn_global_load_lds(
                        (const __attribute__((address_space(1))) void*)(rowS4[rg] + m * mStride + d0c),
                        (__attribute__((address_space(3))) void*)(dH + m * 1024 + rg * 256 + tid),
                        16, 0, 0);
        };
        auto stageW = [&](int buf, int s) {
            const float4* src = wPreT + s * 1792;
            float4* dst = (float4*)&wB[buf][0];
#pragma unroll
            for (int it = 0; it < 7; ++it)
                __builtin_amdgcn_global_load_lds(
                    (const __attribute__((address_space(1))) void*)(src + it * 256 + tid),
                    (__attribute__((address_space(3))) void*)(dst + it * 256 + tid),
                    16, 0, 0);
        };

        f32x4 acc[3][7];
#pragma unroll
        for (int m = 0; m < 3; ++m)
#pragma unroll
            for (int nt = 0; nt < 7; ++nt) acc[m][nt] = (f32x4){0.f, 0.f, 0.f, 0.f};

        // compute one K=32 kstep from stgH[cb] (kstep j) and wB[j]
        auto kstep = [&](const float4* cs, int j) {
            bf16x8 Ahi[3], Alo[3];
#pragma unroll
            for (int m = 0; m < 3; ++m) {
                const float4* rp = cs + m * 1024 + aBase;
                float4 x0 = rp[(j * 8 + 2 * lg) ^ Sa];
                float4 x1 = rp[(j * 8 + 2 * lg + 1) ^ Sa];
#pragma unroll
                for (int q = 0; q < 4; ++q) {
                    float v0 = ((const float*)&x0)[q];
                    unsigned short hh = bfhi(v0);
                    Ahi[m][q] = (short)hh;
                    Alo[m][q] = (short)bfhi(v0 - bfback(hh));
                }
#pragma unroll
                for (int q = 0; q < 4; ++q) {
                    float v1 = ((const float*)&x1)[q];
                    unsigned short hh = bfhi(v1);
                    Ahi[m][4 + q] = (short)hh;
                    Alo[m][4 + q] = (short)bfhi(v1 - bfback(hh));
                }
            }
#pragma unroll
            for (int nt = 0; nt < 7; ++nt) {
                const int n = nt * 16 + ln;
                const int slotP = n ^ ((n >> 3) & 7);
                bf16x8 B[2][2];
#pragma unroll
                for (int mat = 0; mat < 2; ++mat)
#pragma unroll
                    for (int hl = 0; hl < 2; ++hl)
                        B[mat][hl] = *(const bf16x8*)&wB[j][(((mat * 2 + hl) * 4 + lg) * 112 + slotP) * 4];
#pragma unroll
                for (int m = 0; m < 3; ++m) {
                    const int mm = (m == 0) ? 0 : 1;
                    acc[m][nt] = __builtin_amdgcn_mfma_f32_16x16x32_bf16(Ahi[m], B[mm][0], acc[m][nt], 0, 0, 0);
                    acc[m][nt] = __builtin_amdgcn_mfma_f32_16x16x32_bf16(Ahi[m], B[mm][1], acc[m][nt], 0, 0, 0);
                    acc[m][nt] = __builtin_amdgcn_mfma_f32_16x16x32_bf16(Alo[m], B[mm][0], acc[m][nt], 0, 0, 0);
                }
            }
        };

        // ---- tile prologue: Lh(0) [12], Lw(0) [7] ----
        stageH(0, 0);
        stageW(0, 0);
        KBAR("0");

#pragma unroll 1
        for (int ch = 0; ch < NC; ++ch) {
            const int d0 = ch * DC;
            const int cb = ch & 1;
            const float4* cs = &stgH[cb][0];

            // === even kstep (j=0) — issue order matters for vmcnt counts ===
            stageW(1, 2 * ch + 1);                       // 7  (oldest this chunk)
            if (ch + 1 < NC) stageH(cb ^ 1, d0 + DC);    // 12
            // fused h_save: de-permuted readback, ascending 256B-run stores,
            // UNCONDITIONAL (padded rows duplicate-write identical bytes)
#pragma unroll
            for (int m = 0; m < 2; ++m)
#pragma unroll
                for (int rg = 0; rg < 4; ++rg) {
                    float4 v = cs[m * 1024 + slotL4[rg]];
                    *(float4*)(rowH4[rg] + m * mStride + d0) = v;   // 8 stores
                }
            kstep(cs, 0);

            if (ch < NC - 1) KBAR("20");   // waits Lw(2ch+1); Lh+stores fly on
            else             KBAR("8");    // last chunk: no Lh in flight

            // === odd kstep (j=1) ===
            if (ch + 1 < NC) stageW(0, 2 * ch + 2);      // 7
            kstep(cs, 1);

            KBAR("0");   // entering next chunk: needs Lh(ch+1) AND Lw(2ch+2)
        }

        // ---- epilogue: bias + relu-combine + out-layer (verified R9) ----
        {
            float sB7[7], dB7[7], woA[7], woB[7];
            bool valn[7];
#pragma unroll
            for (int nt = 0; nt < 7; ++nt) {
                int n = nt * 16 + ln;
                valn[nt] = (n < H_);
                int nc = valn[nt] ? n : (H_ - 1);
                sB7[nt] = srcB[t * H_ + nc];
                dB7[nt] = dstB[t * H_ + nc];
                float2 wo = *(const float2*)(outW + (size_t)t * H_ * C_ + nc * C_);
                woA[nt] = wo.x; woB[nt] = wo.y;
            }

            float v16[16];
#pragma unroll
            for (int i = 0; i < 16; ++i) v16[i] = 0.f;
#pragma unroll
            for (int nt = 0; nt < 7; ++nt)
#pragma unroll
                for (int reg = 0; reg < 4; ++reg) {
                    float sv = acc[0][nt][reg] + sB7[nt] + dB7[nt];
                    float pe = fmaxf(acc[1][nt][reg] + sv, 0.f);
                    float ne = fmaxf(acc[2][nt][reg] + sv, 0.f);
                    pe = valn[nt] ? pe : 0.f;
                    ne = valn[nt] ? ne : 0.f;
                    v16[reg * 2 + 0]     = fmaf(pe, woA[nt], v16[reg * 2 + 0]);
                    v16[reg * 2 + 1]     = fmaf(pe, woB[nt], v16[reg * 2 + 1]);
                    v16[8 + reg * 2 + 0] = fmaf(ne, woA[nt], v16[8 + reg * 2 + 0]);
                    v16[8 + reg * 2 + 1] = fmaf(ne, woB[nt], v16[8 + reg * 2 + 1]);
                }

            float tot = fold16(v16, ln);   // lane ln: idx = pn*8 + reg*2 + c
            const int c   = ln & 1;
            const int reg = (ln >> 1) & 3;
            const int pn  = ln >> 3;
            const int e   = w * 16 + lg * 4 + reg;
            if (i0 + e < cnt) {
                float val = tot + outB[t * C_ + c];
                size_t pidx = (size_t)(base + i0 + e) * C_ + c;
                out[(pn ? (size_t)C_ * E : (size_t)0) + pidx] = val;
            }
        }

        // ---- steal next tile ----
        __syncthreads();               // full drain; guards LDS reuse
        if (tid == 0) sNext = atomicAdd(ctr, 1);
        __syncthreads();
        tile = sNext;
    }
}

// ---------------------------------------------------------------------------
extern "C" void kernel_launch(void* const* d_in, const int* in_sizes, int n_in,
                              void* d_out, int out_size, void* d_ws, size_t ws_size,
                              hipStream_t stream) {
    (void)n_in; (void)out_size; (void)ws_size;
    const float* h    = (const float*)d_in[0];
    const float* srcW = (const float*)d_in[1];
    const float* srcB = (const float*)d_in[2];
    const float* dstW = (const float*)d_in[3];
    const float* dstB = (const float*)d_in[4];
    const float* outW = (const float*)d_in[5];
    const float* outB = (const float*)d_in[6];
    const int*   et   = (const int*)d_in[7];
    const int E = in_sizes[7];

    float* out = (float*)d_out;
    int* ws = (int*)d_ws;
    int* typeBase  = ws;
    int* typeCount = ws + 8;
    int* tileBase  = ws + 16;
    int* ctr       = ws + WS_CTR;
    int* hist      = ws + WS_HIST;
    int* sorted_e  = ws + WS_SORTED;
    unsigned* wPre = (unsigned*)(ws + WS_WPRE);

    const int seg = (E + SB - 1) / SB;
    k_hist<<<SB, STH, 0, stream>>>(et, E, seg, hist);
    k_scan<<<1, SB, 0, stream>>>(hist, typeBase, typeCount, tileBase, ctr, GRID_MAIN);
    k_scatter<<<SB, STH, 0, stream>>>(et, E, seg, hist, sorted_e);
    k_prew<<<448, 256, 0, stream>>>(srcW, dstW, wPre);

    k_main<<<GRID_MAIN, NTH, 0, stream>>>(h, srcB, dstB, outW, outB,
                                          sorted_e, typeBase, typeCount, tileBase,
                                          wPre, ctr, out, E);
}